// Round 2
// baseline (5709.771 us; speedup 1.0000x reference)
//
#include <hip/hip_runtime.h>
#include <hip/hip_bf16.h>

typedef __hip_bfloat16 bf16;
typedef __attribute__((ext_vector_type(8))) short bf16x8;
typedef __attribute__((ext_vector_type(4))) float f32x4;

#define GLDS16(g, l)                                                  \
  __builtin_amdgcn_global_load_lds(                                   \
      (const __attribute__((address_space(1))) void*)(g),             \
      (__attribute__((address_space(3))) void*)(l), 16, 0, 0)

__device__ __forceinline__ float bf2f(bf16 v) { return __bfloat162float(v); }
__device__ __forceinline__ short f2bf(float f) {
  bf16 b = __float2bfloat16(f);
  return *reinterpret_cast<short*>(&b);
}

// ---------------------------------------------------------------------------
// f32 -> bf16 conversion (for Wh matrices), 8 elems/thread
// ---------------------------------------------------------------------------
__global__ __launch_bounds__(256) void cvt_bf16(const float* __restrict__ in,
                                                bf16* __restrict__ out, int n) {
  const int i = (blockIdx.x * 256 + threadIdx.x) * 8;
  if (i >= n) return;
  const float4 u = *(const float4*)(in + i);
  const float4 v = *(const float4*)(in + i + 4);
  bf16x8 w;
  w[0] = f2bf(u.x); w[1] = f2bf(u.y); w[2] = f2bf(u.z); w[3] = f2bf(u.w);
  w[4] = f2bf(v.x); w[5] = f2bf(v.y); w[6] = f2bf(v.z); w[7] = f2bf(v.w);
  *(bf16x8*)(out + i) = w;
}

// ---------------------------------------------------------------------------
// Prologue: Gi[M=32768][N=3072] = X[M][1024] @ Wi[N][1024]^T + bi   (bf16 out)
// X, Wi are f32; reg-stage + convert to bf16 LDS tiles.
// 128x128 tile, BK=32, 4 waves (2x2), each wave 64x64 = 4x4 frags 16x16x32.
// ---------------------------------------------------------------------------
__global__ __launch_bounds__(256) void gi_gemm(const float* __restrict__ X,
                                               const float* __restrict__ Wi,
                                               const float* __restrict__ bi,
                                               bf16* __restrict__ Gi) {
  __shared__ bf16 As[128 * 32];
  __shared__ bf16 Bs[128 * 32];
  const int tid = threadIdx.x;
  const int lane = tid & 63;
  const int w = tid >> 6;
  const int wm = w >> 1, wn = w & 1;
  const int m0 = blockIdx.y * 128;
  const int n0 = blockIdx.x * 128;
  const int rA = lane & 15;
  const int kl = (lane >> 4) * 8;

  f32x4 acc[4][4] = {};

  const float* Ab = X + (size_t)m0 * 1024;
  const float* Bb = Wi + (size_t)n0 * 1024;

  for (int kt = 0; kt < 1024; kt += 32) {
    // stage: chunk c (0..511): row=c>>2, kk=(c&3)*8 ; thread does c=tid, 256+tid
#pragma unroll
    for (int i = 0; i < 2; ++i) {
      const int c = i * 256 + tid;
      const int row = c >> 2;
      const int kk = (c & 3) * 8;
      const float* sa = Ab + (size_t)row * 1024 + kt + kk;
      const float* sb = Bb + (size_t)row * 1024 + kt + kk;
      const float4 a0 = *(const float4*)sa;
      const float4 a1 = *(const float4*)(sa + 4);
      const float4 b0 = *(const float4*)sb;
      const float4 b1 = *(const float4*)(sb + 4);
      bf16x8 av, bv;
      av[0] = f2bf(a0.x); av[1] = f2bf(a0.y); av[2] = f2bf(a0.z); av[3] = f2bf(a0.w);
      av[4] = f2bf(a1.x); av[5] = f2bf(a1.y); av[6] = f2bf(a1.z); av[7] = f2bf(a1.w);
      bv[0] = f2bf(b0.x); bv[1] = f2bf(b0.y); bv[2] = f2bf(b0.z); bv[3] = f2bf(b0.w);
      bv[4] = f2bf(b1.x); bv[5] = f2bf(b1.y); bv[6] = f2bf(b1.z); bv[7] = f2bf(b1.w);
      *(bf16x8*)(As + c * 8) = av;
      *(bf16x8*)(Bs + c * 8) = bv;
    }
    __syncthreads();

    bf16x8 a[4], b[4];
#pragma unroll
    for (int f = 0; f < 4; ++f) {
      a[f] = *(const bf16x8*)(As + (wm * 64 + f * 16 + rA) * 32 + kl);
      b[f] = *(const bf16x8*)(Bs + (wn * 64 + f * 16 + rA) * 32 + kl);
    }
#pragma unroll
    for (int mf = 0; mf < 4; ++mf)
#pragma unroll
      for (int nf = 0; nf < 4; ++nf)
        acc[mf][nf] = __builtin_amdgcn_mfma_f32_16x16x32_bf16(
            a[mf], b[nf], acc[mf][nf], 0, 0, 0);
    __syncthreads();
  }

  const int rgrp = (lane >> 4) * 4;
#pragma unroll
  for (int nf = 0; nf < 4; ++nf) {
    const int col = n0 + wn * 64 + nf * 16 + rA;
    const float bv = bi[col];
#pragma unroll
    for (int mf = 0; mf < 4; ++mf) {
#pragma unroll
      for (int j = 0; j < 4; ++j) {
        const int row = m0 + wm * 64 + mf * 16 + rgrp + j;
        Gi[(size_t)row * 3072 + col] = __float2bfloat16(acc[mf][nf][j] + bv);
      }
    }
  }
}

// ---------------------------------------------------------------------------
// One recurrent step, both directions (blockIdx.z). Grid (16 coltiles, 4
// batchtiles, 2 dirs), 256 threads = 4 waves; wave w owns 16 cols.
// gh = h_in @ Wh^T (3 gates, 32x16 out per wave), then fused gate math.
// h tile (32x1024 bf16 = 64 KB) staged via global_load_lds with chunk-XOR
// swizzle (pre-swizzled global source, linear LDS dest).
// ---------------------------------------------------------------------------
__global__ __launch_bounds__(256) void gru_step(
    const bf16* __restrict__ Whb, const float* __restrict__ bh_f,
    const float* __restrict__ bh_r, const bf16* __restrict__ Gi,
    const float* __restrict__ mask, bf16* __restrict__ h16,
    float* __restrict__ h32, float* __restrict__ out, int t) {
  __shared__ bf16 hs[32 * 1024];
  const int tid = threadIdx.x;
  const int lane = tid & 63;
  const int w = tid >> 6;
  const int dir = blockIdx.z;
  const int time = dir ? (255 - t) : t;
  const int p = t & 1;

  const bf16* Wh = Whb + (size_t)dir * 3145728;
  const float* bh = dir ? bh_r : bh_f;
  const bf16* gi = Gi + (size_t)dir * (32768ull * 3072ull);
  const bf16* hin = h16 + (size_t)(dir * 2 + p) * 131072;
  bf16* hout = h16 + (size_t)(dir * 2 + (p ^ 1)) * 131072;
  const float* hin32 = h32 + (size_t)(dir * 2 + p) * 131072;
  float* hout32 = h32 + (size_t)(dir * 2 + (p ^ 1)) * 131072;

  const int b0 = blockIdx.y * 32;
  const int c0 = blockIdx.x * 64;

  // Stage h tile: LDS[r][ch] = global[r][ch ^ (r&7)]  (chunks of 8 bf16)
#pragma unroll
  for (int i = 0; i < 16; ++i) {
    const int idx = i * 256 + tid;
    const int r = idx >> 7;        // row 0..31
    const int ch = idx & 127;      // chunk 0..127
    const int gch = ch ^ (r & 7);
    GLDS16(hin + (size_t)(b0 + r) * 1024 + gch * 8,
           hs + (size_t)(i * 256 + w * 64) * 8);
  }
  asm volatile("s_waitcnt vmcnt(0)" ::: "memory");
  __syncthreads();

  const int rA = lane & 15;
  const int klane = lane >> 4;
  const int colg = c0 + w * 16 + rA;  // output col 0..1023 (this lane's n)
  const bf16* bp = Wh + (size_t)colg * 1024 + klane * 8;

  f32x4 acc[3][2] = {};
#pragma unroll 4
  for (int kk = 0; kk < 32; ++kk) {
    const int cidx = kk * 4 + klane;
    const int r1 = 16 + rA;
    bf16x8 a0 = *(const bf16x8*)(hs + rA * 1024 + ((cidx ^ (rA & 7)) << 3));
    bf16x8 a1 = *(const bf16x8*)(hs + r1 * 1024 + ((cidx ^ (r1 & 7)) << 3));
    bf16x8 bg0 = *(const bf16x8*)(bp + kk * 32);
    bf16x8 bg1 = *(const bf16x8*)(bp + 1048576 + kk * 32);
    bf16x8 bg2 = *(const bf16x8*)(bp + 2097152 + kk * 32);
    acc[0][0] = __builtin_amdgcn_mfma_f32_16x16x32_bf16(a0, bg0, acc[0][0], 0, 0, 0);
    acc[0][1] = __builtin_amdgcn_mfma_f32_16x16x32_bf16(a1, bg0, acc[0][1], 0, 0, 0);
    acc[1][0] = __builtin_amdgcn_mfma_f32_16x16x32_bf16(a0, bg1, acc[1][0], 0, 0, 0);
    acc[1][1] = __builtin_amdgcn_mfma_f32_16x16x32_bf16(a1, bg1, acc[1][1], 0, 0, 0);
    acc[2][0] = __builtin_amdgcn_mfma_f32_16x16x32_bf16(a0, bg2, acc[2][0], 0, 0, 0);
    acc[2][1] = __builtin_amdgcn_mfma_f32_16x16x32_bf16(a1, bg2, acc[2][1], 0, 0, 0);
  }

  const float bhr = bh[colg];
  const float bhz = bh[1024 + colg];
  const float bhn = bh[2048 + colg];
#pragma unroll
  for (int m = 0; m < 2; ++m) {
#pragma unroll
    for (int j = 0; j < 4; ++j) {
      const int brow = b0 + m * 16 + klane * 4 + j;
      const size_t gbase = ((size_t)brow * 256 + time) * 3072 + colg;
      const float gr = acc[0][m][j] + bhr + bf2f(gi[gbase]);
      const float gz = acc[1][m][j] + bhz + bf2f(gi[gbase + 1024]);
      const float ghn = acc[2][m][j] + bhn;
      const float r = 1.f / (1.f + __expf(-gr));
      const float z = 1.f / (1.f + __expf(-gz));
      const float nin = bf2f(gi[gbase + 2048]) + r * ghn;
      const float n = 1.f - 2.f / (__expf(2.f * nin) + 1.f);  // tanh(nin)
      const float hp = hin32[(size_t)brow * 1024 + colg];
      float hn = (1.f - z) * n + z * hp;
      const float mk = mask[brow * 256 + time];
      hn = mk * hn + (1.f - mk) * hp;
      hout32[(size_t)brow * 1024 + colg] = hn;
      hout[(size_t)brow * 1024 + colg] = __float2bfloat16(hn);
      out[((size_t)brow * 256 + time) * 2048 + (size_t)(dir * 1024) + colg] = hn;
    }
  }
}

// ---------------------------------------------------------------------------
extern "C" void kernel_launch(void* const* d_in, const int* in_sizes, int n_in,
                              void* d_out, int out_size, void* d_ws,
                              size_t ws_size, hipStream_t stream) {
  const float* x = (const float*)d_in[0];
  const float* mask = (const float*)d_in[1];
  const float* Wi_f = (const float*)d_in[2];
  const float* Wh_f = (const float*)d_in[3];
  const float* bi_f = (const float*)d_in[4];
  const float* bh_f = (const float*)d_in[5];
  const float* Wi_r = (const float*)d_in[6];
  const float* Wh_r = (const float*)d_in[7];
  const float* bi_r = (const float*)d_in[8];
  const float* bh_r = (const float*)d_in[9];
  float* out = (float*)d_out;

  char* ws = (char*)d_ws;
  const size_t GI_ELEMS = 32768ull * 3072ull;  // per dir
  bf16* Gi = (bf16*)ws;                                      // 402.7 MB
  bf16* Whb = (bf16*)(ws + 2 * GI_ELEMS * sizeof(bf16));     // 12.6 MB
  bf16* h16 = Whb + 2 * 3145728;                             // 1 MB
  float* h32 = (float*)(h16 + 4 * 131072);                   // 2 MB

  // zero initial h state (bf16 ping-pong + f32 ping-pong, contiguous)
  hipMemsetAsync(h16, 0, 4 * 131072 * (sizeof(bf16) + sizeof(float)), stream);

  // convert Wh matrices to bf16
  cvt_bf16<<<1536, 256, 0, stream>>>(Wh_f, Whb, 3145728);
  cvt_bf16<<<1536, 256, 0, stream>>>(Wh_r, Whb + 3145728, 3145728);

  gi_gemm<<<dim3(24, 256), 256, 0, stream>>>(x, Wi_f, bi_f, Gi);
  gi_gemm<<<dim3(24, 256), 256, 0, stream>>>(x, Wi_r, bi_r, Gi + GI_ELEMS);

  for (int t = 0; t < 256; ++t)
    gru_step<<<dim3(16, 4, 2), 256, 0, stream>>>(Whb, bh_f, bh_r, Gi, mask,
                                                 h16, h32, out, t);
}

// Round 3
// 4314.642 us; speedup vs baseline: 1.3233x; 1.3233x over previous
//
#include <hip/hip_runtime.h>
#include <hip/hip_bf16.h>

typedef __hip_bfloat16 bf16;
typedef __attribute__((ext_vector_type(8))) short bf16x8;
typedef __attribute__((ext_vector_type(4))) float f32x4;

#define GLDS16(g, l)                                                  \
  __builtin_amdgcn_global_load_lds(                                   \
      (const __attribute__((address_space(1))) void*)(g),             \
      (__attribute__((address_space(3))) void*)(l), 16, 0, 0)

__device__ __forceinline__ float bf2f(bf16 v) { return __bfloat162float(v); }
__device__ __forceinline__ short f2bf(float f) {
  bf16 b = __float2bfloat16(f);
  return *reinterpret_cast<short*>(&b);
}

// ---------------------------------------------------------------------------
// f32 -> bf16 linear conversion, 8 elems/thread
// ---------------------------------------------------------------------------
__global__ __launch_bounds__(256) void cvt_bf16(const float* __restrict__ in,
                                                bf16* __restrict__ out, int n) {
  const int i = (blockIdx.x * 256 + threadIdx.x) * 8;
  if (i >= n) return;
  const float4 u = *(const float4*)(in + i);
  const float4 v = *(const float4*)(in + i + 4);
  bf16x8 w;
  w[0] = f2bf(u.x); w[1] = f2bf(u.y); w[2] = f2bf(u.z); w[3] = f2bf(u.w);
  w[4] = f2bf(v.x); w[5] = f2bf(v.y); w[6] = f2bf(v.z); w[7] = f2bf(v.w);
  *(bf16x8*)(out + i) = w;
}

// ---------------------------------------------------------------------------
// Wh (f32, [3072][1024] per dir) -> bf16 in MFMA B-fragment order:
// Whb[dir][cg(64)][gate(3)][kk(32)][lane(64)][8]
//   fragment (cg,gate,kk), lane l holds Wh[gate*1024 + cg*16 + (l&15)]
//                                       [kk*32 + (l>>4)*8 .. +7]
// Step kernel then loads B-frags as fully coalesced 1KB/wave L2 reads.
// ---------------------------------------------------------------------------
__global__ __launch_bounds__(256) void cvt_whb(const float* __restrict__ Wh_f,
                                               const float* __restrict__ Wh_r,
                                               bf16* __restrict__ Whb) {
  const int t = blockIdx.x * 256 + threadIdx.x;  // 786432 threads
  const int d = t / 393216;
  int r = t % 393216;
  const int cg = r / 6144;  r %= 6144;
  const int g = r / 2048;   r %= 2048;
  const int kk = r / 64;
  const int lane = r & 63;
  const float* Wh = d ? Wh_r : Wh_f;
  const int row = g * 1024 + cg * 16 + (lane & 15);
  const int col = kk * 32 + (lane >> 4) * 8;
  const float* s = Wh + (size_t)row * 1024 + col;
  const float4 u = *(const float4*)s;
  const float4 v = *(const float4*)(s + 4);
  bf16x8 w;
  w[0] = f2bf(u.x); w[1] = f2bf(u.y); w[2] = f2bf(u.z); w[3] = f2bf(u.w);
  w[4] = f2bf(v.x); w[5] = f2bf(v.y); w[6] = f2bf(v.z); w[7] = f2bf(v.w);
  *(bf16x8*)(Whb + (size_t)t * 8) = w;
}

// ---------------------------------------------------------------------------
// Prologue: Gi[32768][3072] = Xb @ Wib^T + bi   (all bf16, m97-style GLDS)
// 128x128 tile, BK=32, 4 waves (2x2), each wave 64x64 = 4x4 frags 16x16x32.
// ---------------------------------------------------------------------------
__global__ __launch_bounds__(256) void gi_gemm(const bf16* __restrict__ X,
                                               const bf16* __restrict__ Wi,
                                               const float* __restrict__ bi,
                                               bf16* __restrict__ Gi) {
  __shared__ bf16 As[128 * 32];
  __shared__ bf16 Bs[128 * 32];
  const int tid = threadIdx.x;
  const int lane = tid & 63;
  const int w = tid >> 6;
  const int wm = w >> 1, wn = w & 1;
  const int m0 = blockIdx.y * 128;
  const int n0 = blockIdx.x * 128;
  const int rA = lane & 15;
  const int kl = (lane >> 4) * 8;

  f32x4 acc[4][4] = {};

  const bf16* Ab = X + (size_t)m0 * 1024;
  const bf16* Bb = Wi + (size_t)n0 * 1024;

  const int arow = tid >> 2;       // staged row (within 64-row half)
  const int akk = (tid & 3) * 8;   // k offset within BK=32

  for (int kt = 0; kt < 1024; kt += 32) {
#pragma unroll
    for (int i = 0; i < 2; ++i) {
      GLDS16(Ab + (size_t)(i * 64 + arow) * 1024 + kt + akk,
             As + (i * 256 + w * 64) * 8);
      GLDS16(Bb + (size_t)(i * 64 + arow) * 1024 + kt + akk,
             Bs + (i * 256 + w * 64) * 8);
    }
    asm volatile("s_waitcnt vmcnt(0)" ::: "memory");
    __syncthreads();

    bf16x8 a[4], b[4];
#pragma unroll
    for (int f = 0; f < 4; ++f) {
      a[f] = *(const bf16x8*)(As + (wm * 64 + f * 16 + rA) * 32 + kl);
      b[f] = *(const bf16x8*)(Bs + (wn * 64 + f * 16 + rA) * 32 + kl);
    }
#pragma unroll
    for (int mf = 0; mf < 4; ++mf)
#pragma unroll
      for (int nf = 0; nf < 4; ++nf)
        acc[mf][nf] = __builtin_amdgcn_mfma_f32_16x16x32_bf16(
            a[mf], b[nf], acc[mf][nf], 0, 0, 0);
    __syncthreads();
  }

  const int rgrp = (lane >> 4) * 4;
#pragma unroll
  for (int nf = 0; nf < 4; ++nf) {
    const int col = n0 + wn * 64 + nf * 16 + rA;
    const float bv = bi[col];
#pragma unroll
    for (int mf = 0; mf < 4; ++mf) {
#pragma unroll
      for (int j = 0; j < 4; ++j) {
        const int row = m0 + wm * 64 + mf * 16 + rgrp + j;
        Gi[(size_t)row * 3072 + col] = __float2bfloat16(acc[mf][nf][j] + bv);
      }
    }
  }
}

// ---------------------------------------------------------------------------
// One recurrent step, both directions. Grid (32 coltiles, 4 batchtiles,
// 2 dirs) = 256 blocks, 256 threads = 4 waves.
// Wave w: m-group mg=w>>1 (16 batch rows), col-group cg=w&1 (16 h-cols);
// 3 gate accumulators; B-frags are coalesced 1KB loads from frag-order Whb.
// h tile (32x1024 bf16 = 64KB) staged via global_load_lds, chunk-XOR swizzle.
// ---------------------------------------------------------------------------
__global__ __launch_bounds__(256) void gru_step(
    const bf16* __restrict__ Whb, const float* __restrict__ bh_f,
    const float* __restrict__ bh_r, const bf16* __restrict__ Gi,
    const float* __restrict__ mask, bf16* __restrict__ h16,
    float* __restrict__ h32, float* __restrict__ out, int t) {
  __shared__ bf16 hs[32 * 1024];
  const int tid = threadIdx.x;
  const int lane = tid & 63;
  const int w = tid >> 6;
  const int dir = blockIdx.z;
  const int time = dir ? (255 - t) : t;
  const int p = t & 1;

  const float* bh = dir ? bh_r : bh_f;
  const bf16* gi = Gi + (size_t)dir * (32768ull * 3072ull);
  const bf16* hin = h16 + (size_t)(dir * 2 + p) * 131072;
  bf16* hout = h16 + (size_t)(dir * 2 + (p ^ 1)) * 131072;
  const float* hin32 = h32 + (size_t)(dir * 2 + p) * 131072;
  float* hout32 = h32 + (size_t)(dir * 2 + (p ^ 1)) * 131072;

  const int bt0 = blockIdx.y * 32;
  const int c0 = blockIdx.x * 32;

  // Stage h tile: LDS[r][ch] = global[r][ch ^ (r&7)]  (chunks of 8 bf16)
#pragma unroll
  for (int i = 0; i < 16; ++i) {
    const int idx = i * 256 + tid;
    const int r = idx >> 7;        // row 0..31
    const int ch = idx & 127;      // chunk 0..127
    const int gch = ch ^ (r & 7);
    GLDS16(hin + (size_t)(bt0 + r) * 1024 + gch * 8,
           hs + (size_t)(i * 256 + w * 64) * 8);
  }
  asm volatile("s_waitcnt vmcnt(0)" ::: "memory");
  __syncthreads();

  const int rA = lane & 15;
  const int klane = lane >> 4;
  const int mg = w >> 1;
  const int cg = w & 1;
  const int row = mg * 16 + rA;       // h row within 32-row tile
  const int colg = c0 + cg * 16 + rA; // global h-col for this lane
  const bf16* bp = Whb + (size_t)dir * 3145728 +
                   (size_t)((blockIdx.x * 2 + cg) * 3) * 16384 + lane * 8;

  f32x4 acc[3] = {};
#pragma unroll 8
  for (int kk = 0; kk < 32; ++kk) {
    const int cidx = kk * 4 + klane;
    bf16x8 a = *(const bf16x8*)(hs + row * 1024 + ((cidx ^ (row & 7)) << 3));
    bf16x8 bg0 = *(const bf16x8*)(bp + kk * 512);
    bf16x8 bg1 = *(const bf16x8*)(bp + 16384 + kk * 512);
    bf16x8 bg2 = *(const bf16x8*)(bp + 32768 + kk * 512);
    acc[0] = __builtin_amdgcn_mfma_f32_16x16x32_bf16(a, bg0, acc[0], 0, 0, 0);
    acc[1] = __builtin_amdgcn_mfma_f32_16x16x32_bf16(a, bg1, acc[1], 0, 0, 0);
    acc[2] = __builtin_amdgcn_mfma_f32_16x16x32_bf16(a, bg2, acc[2], 0, 0, 0);
  }

  const float bhr = bh[colg];
  const float bhz = bh[1024 + colg];
  const float bhn = bh[2048 + colg];
#pragma unroll
  for (int j = 0; j < 4; ++j) {
    const int brow = bt0 + mg * 16 + klane * 4 + j;
    const size_t gbase = ((size_t)brow * 256 + time) * 3072 + colg;
    const float gr = acc[0][j] + bhr + bf2f(gi[gbase]);
    const float gz = acc[1][j] + bhz + bf2f(gi[gbase + 1024]);
    const float ghn = acc[2][j] + bhn;
    const float r = 1.f / (1.f + __expf(-gr));
    const float z = 1.f / (1.f + __expf(-gz));
    const float nin = bf2f(gi[gbase + 2048]) + r * ghn;
    const float n = 1.f - 2.f / (__expf(2.f * nin) + 1.f);  // tanh(nin)
    const float hp = hin32[(size_t)brow * 1024 + colg];
    float hn = (1.f - z) * n + z * hp;
    const float mk = mask[brow * 256 + time];
    hn = mk * hn + (1.f - mk) * hp;
    hout32[(size_t)brow * 1024 + colg] = hn;
    hout[(size_t)brow * 1024 + colg] = __float2bfloat16(hn);
    out[((size_t)brow * 256 + time) * 2048 + (size_t)(dir * 1024) + colg] = hn;
  }
}

// ---------------------------------------------------------------------------
extern "C" void kernel_launch(void* const* d_in, const int* in_sizes, int n_in,
                              void* d_out, int out_size, void* d_ws,
                              size_t ws_size, hipStream_t stream) {
  const float* x = (const float*)d_in[0];
  const float* mask = (const float*)d_in[1];
  const float* Wi_f = (const float*)d_in[2];
  const float* Wh_f = (const float*)d_in[3];
  const float* bi_f = (const float*)d_in[4];
  const float* bh_f = (const float*)d_in[5];
  const float* Wi_r = (const float*)d_in[6];
  const float* Wh_r = (const float*)d_in[7];
  const float* bi_r = (const float*)d_in[8];
  const float* bh_r = (const float*)d_in[9];
  float* out = (float*)d_out;

  char* ws = (char*)d_ws;
  const size_t GI_ELEMS = 32768ull * 3072ull;  // per dir
  bf16* Gi = (bf16*)ws;                                   // 402.7 MB
  bf16* Whb = (bf16*)(ws + 2 * GI_ELEMS * sizeof(bf16));  // 12.6 MB (frag ord)
  bf16* h16 = Whb + 2 * 3145728;                          // 1 MB
  float* h32 = (float*)(h16 + 4 * 131072);                // 2 MB

  // bf16 X / Wi scratch lives in d_out (fully overwritten by gru_steps later)
  bf16* Xb = (bf16*)d_out;                 // 33.5M elems = 67 MB
  bf16* Wib_f = Xb + 33554432;             // 3.1M elems
  bf16* Wib_r = Wib_f + 3145728;           // 3.1M elems (total 79.7 < 248 MB)

  // zero initial h state (bf16 ping-pong + f32 ping-pong, contiguous)
  hipMemsetAsync(h16, 0, 4 * 131072 * (sizeof(bf16) + sizeof(float)), stream);

  cvt_bf16<<<16384, 256, 0, stream>>>(x, Xb, 33554432);
  cvt_bf16<<<1536, 256, 0, stream>>>(Wi_f, Wib_f, 3145728);
  cvt_bf16<<<1536, 256, 0, stream>>>(Wi_r, Wib_r, 3145728);
  cvt_whb<<<3072, 256, 0, stream>>>(Wh_f, Wh_r, Whb);

  gi_gemm<<<dim3(24, 256), 256, 0, stream>>>(Xb, Wib_f, bi_f, Gi);
  gi_gemm<<<dim3(24, 256), 256, 0, stream>>>(Xb, Wib_r, bi_r, Gi + GI_ELEMS);

  for (int t = 0; t < 256; ++t)
    gru_step<<<dim3(32, 4, 2), 256, 0, stream>>>(Whb, bh_f, bh_r, Gi, mask,
                                                 h16, h32, out, t);
}

// Round 6
// 2427.131 us; speedup vs baseline: 2.3525x; 1.7777x over previous
//
#include <hip/hip_runtime.h>
#include <hip/hip_bf16.h>

typedef __hip_bfloat16 bf16;
typedef __attribute__((ext_vector_type(8))) short bf16x8;
typedef __attribute__((ext_vector_type(4))) float f32x4;

#define GLDS16(g, l)                                                  \
  __builtin_amdgcn_global_load_lds(                                   \
      (const __attribute__((address_space(1))) void*)(g),             \
      (__attribute__((address_space(3))) void*)(l), 16, 0, 0)

__device__ __forceinline__ float bf2f(bf16 v) { return __bfloat162float(v); }
__device__ __forceinline__ short f2bf(float f) {
  bf16 b = __float2bfloat16(f);
  return *reinterpret_cast<short*>(&b);
}

// ---------------------------------------------------------------------------
// f32 -> bf16 linear conversion, 8 elems/thread
// ---------------------------------------------------------------------------
__global__ __launch_bounds__(256) void cvt_bf16(const float* __restrict__ in,
                                                bf16* __restrict__ out, int n) {
  const int i = (blockIdx.x * 256 + threadIdx.x) * 8;
  if (i >= n) return;
  const float4 u = *(const float4*)(in + i);
  const float4 v = *(const float4*)(in + i + 4);
  bf16x8 w;
  w[0] = f2bf(u.x); w[1] = f2bf(u.y); w[2] = f2bf(u.z); w[3] = f2bf(u.w);
  w[4] = f2bf(v.x); w[5] = f2bf(v.y); w[6] = f2bf(v.z); w[7] = f2bf(v.w);
  *(bf16x8*)(out + i) = w;
}

// ---------------------------------------------------------------------------
// Wh (f32, [3072][1024] per dir) -> bf16 in MFMA B-fragment order:
// Whb[dir][cg(64)][gate(3)][kk(32)][lane(64)][8]
// ---------------------------------------------------------------------------
__global__ __launch_bounds__(256) void cvt_whb(const float* __restrict__ Wh_f,
                                               const float* __restrict__ Wh_r,
                                               bf16* __restrict__ Whb) {
  const int t = blockIdx.x * 256 + threadIdx.x;  // 786432 threads
  const int d = t / 393216;
  int r = t % 393216;
  const int cg = r / 6144;  r %= 6144;
  const int g = r / 2048;   r %= 2048;
  const int kk = r / 64;
  const int lane = r & 63;
  const float* Wh = d ? Wh_r : Wh_f;
  const int row = g * 1024 + cg * 16 + (lane & 15);
  const int col = kk * 32 + (lane >> 4) * 8;
  const float* s = Wh + (size_t)row * 1024 + col;
  const float4 u = *(const float4*)s;
  const float4 v = *(const float4*)(s + 4);
  bf16x8 w;
  w[0] = f2bf(u.x); w[1] = f2bf(u.y); w[2] = f2bf(u.z); w[3] = f2bf(u.w);
  w[4] = f2bf(v.x); w[5] = f2bf(v.y); w[6] = f2bf(v.z); w[7] = f2bf(v.w);
  *(bf16x8*)(Whb + (size_t)t * 8) = w;
}

// ---------------------------------------------------------------------------
// Prologue: Gi[32768][3072] = Xb @ Wib^T + bi   (all bf16, m97-style GLDS)
// ---------------------------------------------------------------------------
__global__ __launch_bounds__(256) void gi_gemm(const bf16* __restrict__ X,
                                               const bf16* __restrict__ Wi,
                                               const float* __restrict__ bi,
                                               bf16* __restrict__ Gi) {
  __shared__ bf16 As[128 * 32];
  __shared__ bf16 Bs[128 * 32];
  const int tid = threadIdx.x;
  const int lane = tid & 63;
  const int w = tid >> 6;
  const int wm = w >> 1, wn = w & 1;
  const int m0 = blockIdx.y * 128;
  const int n0 = blockIdx.x * 128;
  const int rA = lane & 15;
  const int kl = (lane >> 4) * 8;

  f32x4 acc[4][4] = {};

  const bf16* Ab = X + (size_t)m0 * 1024;
  const bf16* Bb = Wi + (size_t)n0 * 1024;

  const int arow = tid >> 2;
  const int akk = (tid & 3) * 8;

  for (int kt = 0; kt < 1024; kt += 32) {
#pragma unroll
    for (int i = 0; i < 2; ++i) {
      GLDS16(Ab + (size_t)(i * 64 + arow) * 1024 + kt + akk,
             As + (i * 256 + w * 64) * 8);
      GLDS16(Bb + (size_t)(i * 64 + arow) * 1024 + kt + akk,
             Bs + (i * 256 + w * 64) * 8);
    }
    asm volatile("s_waitcnt vmcnt(0)" ::: "memory");
    __syncthreads();

    bf16x8 a[4], b[4];
#pragma unroll
    for (int f = 0; f < 4; ++f) {
      a[f] = *(const bf16x8*)(As + (wm * 64 + f * 16 + rA) * 32 + kl);
      b[f] = *(const bf16x8*)(Bs + (wn * 64 + f * 16 + rA) * 32 + kl);
    }
#pragma unroll
    for (int mf = 0; mf < 4; ++mf)
#pragma unroll
      for (int nf = 0; nf < 4; ++nf)
        acc[mf][nf] = __builtin_amdgcn_mfma_f32_16x16x32_bf16(
            a[mf], b[nf], acc[mf][nf], 0, 0, 0);
    __syncthreads();
  }

  const int rgrp = (lane >> 4) * 4;
#pragma unroll
  for (int nf = 0; nf < 4; ++nf) {
    const int col = n0 + wn * 64 + nf * 16 + rA;
    const float bv = bi[col];
#pragma unroll
    for (int mf = 0; mf < 4; ++mf) {
#pragma unroll
      for (int j = 0; j < 4; ++j) {
        const int row = m0 + wm * 64 + mf * 16 + rgrp + j;
        Gi[(size_t)row * 3072 + col] = __float2bfloat16(acc[mf][nf][j] + bv);
      }
    }
  }
}

// ---------------------------------------------------------------------------
// Persistent recurrence, REGULAR launch (R4 proved 256 blocks co-reside and
// the flag barrier runs to completion). Grid (32 ct, 4 bt, 2 dir) = 256
// blocks, 256 threads = 4 waves (mg x cg).
// 8 independent chains (dir x bt); per-chain 32-slot flag barrier.
// ALL cross-step data (h, flags) moves via sc0/sc1-bypass agent atomics at
// native widths (32b packed stores, 64b loads); everything else (Whb, Gi,
// mask, biases) is immutable -> stale L2 is safe, no acquire fences -> L2
// stays hot. Wh r,z fragments register-resident; n gate streamed from L2.
// ---------------------------------------------------------------------------
__global__ __launch_bounds__(256, 1) void gru_persist(
    const bf16* __restrict__ Whb, const float* __restrict__ bh_f,
    const float* __restrict__ bh_r, const bf16* __restrict__ Gi,
    const float* __restrict__ mask, bf16* __restrict__ h16,
    unsigned int* __restrict__ flags, float* __restrict__ out) {
  __shared__ bf16 hs[32 * 1024];
  const int tid = threadIdx.x;
  const int lane = tid & 63;
  const int w = tid >> 6;
  const int mg = w >> 1;
  const int cg = w & 1;
  const int ct = blockIdx.x;       // 0..31 col tile
  const int bt = blockIdx.y;       // 0..3 batch tile
  const int dir = blockIdx.z;      // 0..1
  unsigned int* gflags = flags + (dir * 4 + bt) * 32;

  const float* bh = dir ? bh_r : bh_f;
  const bf16* gi = Gi + (size_t)dir * (32768ull * 3072ull);
  const int bt0 = bt * 32;
  const int c0 = ct * 32;

  const int rA = lane & 15;
  const int klane = lane >> 4;
  const int row = mg * 16 + rA;        // h row within 32-row tile
  const int colg = c0 + cg * 16 + rA;  // global h-col for this lane

  // --- r,z gate B-fragments into registers (once); n gate streamed ---
  const bf16* bpb = Whb + (size_t)dir * 3145728 +
                    (size_t)((ct * 2 + cg) * 3) * 16384 + lane * 8;
  bf16x8 br[32], bz[32];
#pragma unroll
  for (int kk = 0; kk < 32; ++kk) br[kk] = *(const bf16x8*)(bpb + kk * 512);
#pragma unroll
  for (int kk = 0; kk < 32; ++kk)
    bz[kk] = *(const bf16x8*)(bpb + 16384 + kk * 512);
  const bf16* bpn = bpb + 32768;

  const float bhr = bh[colg];
  const float bhz = bh[1024 + colg];
  const float bhn = bh[2048 + colg];

  float hp[4] = {0.f, 0.f, 0.f, 0.f};
  const int brow0 = bt0 + mg * 16 + klane * 4;

  for (int t = 0; t < 256; ++t) {
    const int p = t & 1;
    const int time = dir ? (255 - t) : t;
    const bf16* hin = h16 + (size_t)(dir * 2 + p) * 131072;
    bf16* hout = h16 + (size_t)(dir * 2 + (p ^ 1)) * 131072;

    // --- stage h tile: 8B bypass loads -> swizzled ds_write_b64 ---
#pragma unroll
    for (int half = 0; half < 2; ++half) {
      unsigned long long vv[16];
#pragma unroll
      for (int q = 0; q < 16; ++q) {
        const int idx = (half * 16 + q) * 256 + tid;
        const int r = idx >> 8;       // row 0..31
        const int c8 = idx & 255;     // 8B chunk within row
        vv[q] = __hip_atomic_load(
            (const unsigned long long*)(hin + ((size_t)(bt0 + r) << 10) +
                                        c8 * 4),
            __ATOMIC_RELAXED, __HIP_MEMORY_SCOPE_AGENT);
      }
#pragma unroll
      for (int q = 0; q < 16; ++q) {
        const int idx = (half * 16 + q) * 256 + tid;
        const int r = idx >> 8;
        const int c8 = idx & 255;
        const int ch = c8 >> 1;       // 16B chunk index 0..127
        const int sw = ((ch ^ (r & 7)) << 4) | ((c8 & 1) << 3);
        *(unsigned long long*)((char*)hs + r * 2048 + sw) = vv[q];
      }
    }

    // --- prefetch gi + mask for this step (immutable, cached) ---
    float gir[4], giz[4], gin[4], mk[4];
#pragma unroll
    for (int j = 0; j < 4; ++j) {
      const int brow = brow0 + j;
      const size_t gbase = ((size_t)brow * 256 + time) * 3072 + colg;
      gir[j] = bf2f(gi[gbase]);
      giz[j] = bf2f(gi[gbase + 1024]);
      gin[j] = bf2f(gi[gbase + 2048]);
      mk[j] = mask[brow * 256 + time];
    }
    __syncthreads();

    // --- gh = h @ Wh^T (3 gates) ---
    f32x4 acc0 = {}, acc1 = {}, acc2 = {};
#pragma unroll
    for (int kk = 0; kk < 32; ++kk) {
      const int cidx = kk * 4 + klane;
      bf16x8 a = *(const bf16x8*)(hs + row * 1024 + ((cidx ^ (row & 7)) << 3));
      bf16x8 bn = *(const bf16x8*)(bpn + kk * 512);
      acc0 = __builtin_amdgcn_mfma_f32_16x16x32_bf16(a, br[kk], acc0, 0, 0, 0);
      acc1 = __builtin_amdgcn_mfma_f32_16x16x32_bf16(a, bz[kk], acc1, 0, 0, 0);
      acc2 = __builtin_amdgcn_mfma_f32_16x16x32_bf16(a, bn, acc2, 0, 0, 0);
    }

    // --- gates + state update; packed dword h stores (native width) ---
#pragma unroll
    for (int j = 0; j < 4; ++j) {
      const int brow = brow0 + j;
      const float gr = acc0[j] + bhr + gir[j];
      const float gz = acc1[j] + bhz + giz[j];
      const float ghn = acc2[j] + bhn;
      const float r = 1.f / (1.f + __expf(-gr));
      const float z = 1.f / (1.f + __expf(-gz));
      const float nin = gin[j] + r * ghn;
      const float n = 1.f - 2.f / (__expf(2.f * nin) + 1.f);  // tanh
      float hn = (1.f - z) * n + z * hp[j];
      hn = mk[j] * hn + (1.f - mk[j]) * hp[j];
      hp[j] = hn;
      out[((size_t)brow * 256 + time) * 2048 + (size_t)(dir * 1024) + colg] =
          hn;
      const unsigned short hb = (unsigned short)f2bf(hn);
      const unsigned nb = (unsigned)__shfl_xor((int)hb, 1);
      if (!(lane & 1)) {
        const unsigned dword = (unsigned)hb | (nb << 16);
        __hip_atomic_store(
            (unsigned int*)(hout + ((size_t)brow << 10) + colg), dword,
            __ATOMIC_RELAXED, __HIP_MEMORY_SCOPE_AGENT);
      }
    }

    // --- chain barrier: drain stores, arrive on own slot, wave0 polls ---
    asm volatile("s_waitcnt vmcnt(0)" ::: "memory");
    __syncthreads();   // all waves drained before tid0 signals
    if (tid == 0)
      __hip_atomic_store(&gflags[ct], (unsigned)(t + 1), __ATOMIC_RELAXED,
                         __HIP_MEMORY_SCOPE_AGENT);
    if (t < 255) {
      if (w == 0) {
        unsigned v;
        do {
          __builtin_amdgcn_s_sleep(1);
          v = __hip_atomic_load(&gflags[lane & 31], __ATOMIC_RELAXED,
                                __HIP_MEMORY_SCOPE_AGENT);
        } while (__any((int)(v < (unsigned)(t + 1))));
      }
      __builtin_amdgcn_sched_barrier(0);
      __syncthreads();
    }
  }
}

// ---------------------------------------------------------------------------
extern "C" void kernel_launch(void* const* d_in, const int* in_sizes, int n_in,
                              void* d_out, int out_size, void* d_ws,
                              size_t ws_size, hipStream_t stream) {
  const float* x = (const float*)d_in[0];
  const float* mask = (const float*)d_in[1];
  const float* Wi_f = (const float*)d_in[2];
  const float* Wh_f = (const float*)d_in[3];
  const float* bi_f = (const float*)d_in[4];
  const float* bh_f = (const float*)d_in[5];
  const float* Wi_r = (const float*)d_in[6];
  const float* Wh_r = (const float*)d_in[7];
  const float* bi_r = (const float*)d_in[8];
  const float* bh_r = (const float*)d_in[9];
  float* out = (float*)d_out;

  char* ws = (char*)d_ws;
  const size_t GI_ELEMS = 32768ull * 3072ull;  // per dir
  bf16* Gi = (bf16*)ws;                                   // 402.7 MB
  bf16* Whb = (bf16*)(ws + 2 * GI_ELEMS * sizeof(bf16));  // 12.6 MB
  bf16* h16 = Whb + 2 * 3145728;                          // 1 MB ping-pong
  unsigned int* flags = (unsigned int*)(h16 + 4 * 131072);  // 1 KB

  // bf16 X / Wi scratch lives in d_out (fully overwritten afterwards)
  bf16* Xb = (bf16*)d_out;
  bf16* Wib_f = Xb + 33554432;
  bf16* Wib_r = Wib_f + 3145728;

  // zero h ping-pong + flags (adjacent)
  hipMemsetAsync(h16, 0, 4 * 131072 * sizeof(bf16) + 256 * sizeof(unsigned),
                 stream);

  cvt_bf16<<<16384, 256, 0, stream>>>(x, Xb, 33554432);
  cvt_bf16<<<1536, 256, 0, stream>>>(Wi_f, Wib_f, 3145728);
  cvt_bf16<<<1536, 256, 0, stream>>>(Wi_r, Wib_r, 3145728);
  cvt_whb<<<3072, 256, 0, stream>>>(Wh_f, Wh_r, Whb);

  gi_gemm<<<dim3(24, 256), 256, 0, stream>>>(Xb, Wib_f, bi_f, Gi);
  gi_gemm<<<dim3(24, 256), 256, 0, stream>>>(Xb, Wib_r, bi_r, Gi + GI_ELEMS);

  gru_persist<<<dim3(32, 4, 2), 256, 0, stream>>>(Whb, bh_f, bh_r, Gi, mask,
                                                  h16, flags, out);
}